// Round 1
// baseline (242.698 us; speedup 1.0000x reference)
//
#include <hip/hip_runtime.h>
#include <hip/hip_bf16.h>
#include <stdint.h>

#define Bb 8
#define Tt 256
#define TCC 768
#define TKV 1024
#define NS 1024
#define NH 16
#define DH 64
#define QK_SCALE 0.125f

typedef short bf16x8 __attribute__((ext_vector_type(8)));
typedef float f32x4 __attribute__((ext_vector_type(4)));

__device__ __forceinline__ unsigned short f2bf(float f) {
  union { float f; uint32_t u; } v; v.f = f;
  uint32_t u = v.u;
  u += 0x7fff + ((u >> 16) & 1);   // round-to-nearest-even
  return (unsigned short)(u >> 16);
}

// ---------------- kernel 1: x -> bf16, cache_k -> bf16 (into concat slot) ----
__global__ void convert_flat(const float* __restrict__ x, const float* __restrict__ ck,
                             unsigned short* __restrict__ xb, unsigned short* __restrict__ kb) {
  const int64_t nx4 = (int64_t)Bb * Tt * NS / 4;        // 524288
  const int64_t nk4 = (int64_t)Bb * TCC * NS / 4;       // 1572864
  int64_t stride = (int64_t)gridDim.x * blockDim.x;
  for (int64_t t = (int64_t)blockIdx.x * blockDim.x + threadIdx.x; t < nx4 + nk4; t += stride) {
    if (t < nx4) {
      float4 v = ((const float4*)x)[t];
      ushort4 o; o.x = f2bf(v.x); o.y = f2bf(v.y); o.z = f2bf(v.z); o.w = f2bf(v.w);
      ((ushort4*)xb)[t] = o;
    } else {
      int64_t e = t - nx4;
      float4 v = ((const float4*)ck)[e];
      ushort4 o; o.x = f2bf(v.x); o.y = f2bf(v.y); o.z = f2bf(v.z); o.w = f2bf(v.w);
      int64_t el = e * 4;
      int64_t b = el / ((int64_t)TCC * NS);
      int64_t rem = el % ((int64_t)TCC * NS);
      int64_t d = b * (int64_t)TKV * NS + rem;          // rows 0..767 of concat K
      ((ushort4*)kb)[d / 4] = o;
    }
  }
}

// ------- kernel 2: W -> bf16 transposed [N][K]; cache_v -> bf16 [b][h][d][t] -
__global__ void transpose_convert(const float* __restrict__ Wq, const float* __restrict__ Wk,
                                  const float* __restrict__ Wv, const float* __restrict__ Wo,
                                  const float* __restrict__ cv,
                                  unsigned short* __restrict__ wqt, unsigned short* __restrict__ wkt,
                                  unsigned short* __restrict__ wvt, unsigned short* __restrict__ wot,
                                  unsigned short* __restrict__ vbt) {
  __shared__ float tile[64][65];
  int bid = blockIdx.x;
  const float* src; unsigned short* dst;
  if (bid < 1024) {                       // 4 weight mats, 16x16 tiles of 64x64
    int mat = bid >> 8, t = bid & 255;
    int tr = t >> 4, tc = t & 15;
    const float* W = (mat == 0) ? Wq : (mat == 1) ? Wk : (mat == 2) ? Wv : Wo;
    unsigned short* Wt = (mat == 0) ? wqt : (mat == 1) ? wkt : (mat == 2) ? wvt : wot;
    src = W + (int64_t)(tr * 64) * 1024 + tc * 64;
    dst = Wt + (int64_t)(tc * 64) * 1024 + tr * 64;
  } else {                                // cache_v: per b, [768][1024] -> [1024][1024] (cols 0..767)
    int e = bid - 1024;                   // 8 * 12 * 16 = 1536 tiles
    int b = e / 192; int t = e % 192;
    int st = t >> 4, ct = t & 15;
    src = cv + (int64_t)b * TCC * NS + (int64_t)(st * 64) * 1024 + ct * 64;
    dst = vbt + (int64_t)b * NS * TKV + (int64_t)(ct * 64) * 1024 + st * 64;
  }
  for (int e = threadIdx.x; e < 4096; e += 256) {
    int i = e >> 6, j = e & 63;
    tile[i][j] = src[(int64_t)i * 1024 + j];
  }
  __syncthreads();
  for (int e = threadIdx.x; e < 4096; e += 256) {
    int i = e >> 6, j = e & 63;
    dst[(int64_t)i * 1024 + j] = f2bf(tile[j][i]);
  }
}

// ---------------- kernel 3/5: bf16 MFMA GEMM, 128x128 tile, BK=32 ------------
// A: [M][1024] bf16 row-major.  Bt: [N][1024] bf16 (i.e. W^T), so fragments are
// contiguous along K.  LDS rows padded to 40 elems (80 B = 16B-aligned, 2-way
// bank aliasing only -> free).
template <int MODE>
__global__ void gemm128(const unsigned short* __restrict__ A,
                        const unsigned short* __restrict__ Bt0, const unsigned short* __restrict__ Bt1,
                        const unsigned short* __restrict__ Bt2,
                        const float* __restrict__ bq, const float* __restrict__ bv,
                        const float* __restrict__ bo,
                        unsigned short* __restrict__ qb,
                        float* __restrict__ okf, float* __restrict__ ovf,
                        unsigned short* __restrict__ kb, unsigned short* __restrict__ vbt,
                        float* __restrict__ outf) {
  __shared__ unsigned short As[128 * 40];
  __shared__ unsigned short Bs[128 * 40];
  int tid = threadIdx.x, lane = tid & 63, w = tid >> 6;
  int lr = lane & 15, hi = lane >> 4;
  int wr = w >> 1, wc = w & 1;

  int tm, seg, col0;
  const unsigned short* Bt;
  if (MODE == 0) {
    tm = blockIdx.x & 15; int tn = blockIdx.x >> 4;        // tn 0..23
    seg = tn >> 3; col0 = (tn & 7) * 128;
    Bt = (seg == 0) ? Bt0 : (seg == 1) ? Bt1 : Bt2;
  } else {
    tm = blockIdx.x & 15; int tn = blockIdx.x >> 4;        // tn 0..7
    seg = 0; col0 = tn * 128;
    Bt = Bt0;
  }
  int m0 = tm * 128;

  f32x4 acc[4][4];
#pragma unroll
  for (int i = 0; i < 4; i++)
#pragma unroll
    for (int j = 0; j < 4; j++) acc[i][j] = (f32x4){0.f, 0.f, 0.f, 0.f};

  for (int k0 = 0; k0 < 1024; k0 += 32) {
#pragma unroll
    for (int e = tid; e < 512; e += 256) {
      int r = e >> 2, kc = (e & 3) * 8;
      *(bf16x8*)&As[r * 40 + kc] = *(const bf16x8*)&A[(int64_t)(m0 + r) * 1024 + k0 + kc];
      *(bf16x8*)&Bs[r * 40 + kc] = *(const bf16x8*)&Bt[(int64_t)(col0 + r) * 1024 + k0 + kc];
    }
    __syncthreads();
    bf16x8 af[4], bf[4];
#pragma unroll
    for (int mt = 0; mt < 4; mt++) af[mt] = *(const bf16x8*)&As[(wr * 64 + mt * 16 + lr) * 40 + hi * 8];
#pragma unroll
    for (int nt = 0; nt < 4; nt++) bf[nt] = *(const bf16x8*)&Bs[(wc * 64 + nt * 16 + lr) * 40 + hi * 8];
#pragma unroll
    for (int mt = 0; mt < 4; mt++)
#pragma unroll
      for (int nt = 0; nt < 4; nt++)
        acc[mt][nt] = __builtin_amdgcn_mfma_f32_16x16x32_bf16(af[mt], bf[nt], acc[mt][nt], 0, 0, 0);
    __syncthreads();
  }

  // epilogue: D[row=(l>>4)*4+r][col=l&15] per 16x16 tile
#pragma unroll
  for (int mt = 0; mt < 4; mt++)
#pragma unroll
    for (int nt = 0; nt < 4; nt++) {
      int row = m0 + wr * 64 + mt * 16 + hi * 4;
      int col = col0 + wc * 64 + nt * 16 + lr;    // segment-local 0..1023
      if (MODE == 1) {
        float bias = bo[col];
#pragma unroll
        for (int r = 0; r < 4; r++)
          outf[(int64_t)(row + r) * 1024 + col] = acc[mt][nt][r] + bias;
      } else if (seg == 0) {                       // q: (acc+bq)*scale -> bf16
        float bias = bq[col];
#pragma unroll
        for (int r = 0; r < 4; r++)
          qb[(int64_t)(row + r) * 1024 + col] = f2bf((acc[mt][nt][r] + bias) * QK_SCALE);
      } else if (seg == 1) {                       // new_k: fp32 out + bf16 concat
#pragma unroll
        for (int r = 0; r < 4; r++) {
          float v = acc[mt][nt][r];
          okf[(int64_t)(row + r) * 1024 + col] = v;
          int b = (row + r) >> 8, t = (row + r) & 255;
          kb[((int64_t)(b * TKV + TCC + t)) * 1024 + col] = f2bf(v);
        }
      } else {                                     // new_v: fp32 out + bf16 transposed concat
        float bias = bv[col];
        int b = row >> 8, t0 = row & 255;
        int64_t voff = ((int64_t)(b * NH + (col >> 6)) * DH + (col & 63)) * TKV + TCC + t0;
        ushort4 pk;
        float v0 = acc[mt][nt][0] + bias, v1 = acc[mt][nt][1] + bias,
              v2 = acc[mt][nt][2] + bias, v3 = acc[mt][nt][3] + bias;
        ovf[(int64_t)(row + 0) * 1024 + col] = v0;
        ovf[(int64_t)(row + 1) * 1024 + col] = v1;
        ovf[(int64_t)(row + 2) * 1024 + col] = v2;
        ovf[(int64_t)(row + 3) * 1024 + col] = v3;
        pk.x = f2bf(v0); pk.y = f2bf(v1); pk.z = f2bf(v2); pk.w = f2bf(v3);
        *(ushort4*)&vbt[voff] = pk;
      }
    }
}

// ---------------- kernel 4: flash attention, bf16 MFMA -----------------------
// grid 512 = B*H*4; block 256 (4 waves x 16 q-rows). KV chunks of 64.
__global__ void attn(const unsigned short* __restrict__ qb, const unsigned short* __restrict__ kb,
                     const unsigned short* __restrict__ vbt, const float* __restrict__ mask,
                     unsigned short* __restrict__ wvb) {
  __shared__ unsigned short Ks[64 * 72];        // [kv][d], pad 72 -> 2-way only
  __shared__ unsigned short Vs[64 * 72];        // [d][kv] (from transposed V)
  __shared__ unsigned short Ps[4][16 * 72];     // per-wave P tile [qrow][kv]
  int tid = threadIdx.x, lane = tid & 63, w = tid >> 6;
  int lr = lane & 15, hi = lane >> 4;
  int qblk = blockIdx.x & 3, bh = blockIdx.x >> 2, b = bh >> 4, h = bh & 15;
  int q0 = qblk * 64 + w * 16;

  const unsigned short* qp = qb + ((int64_t)(b * Tt + q0 + lr)) * 1024 + h * DH + hi * 8;
  bf16x8 aq0 = *(const bf16x8*)qp;
  bf16x8 aq1 = *(const bf16x8*)(qp + 32);

  f32x4 o[4];
#pragma unroll
  for (int nt = 0; nt < 4; nt++) o[nt] = (f32x4){0.f, 0.f, 0.f, 0.f};
  float m[4] = {-1e30f, -1e30f, -1e30f, -1e30f};
  float l[4] = {0.f, 0.f, 0.f, 0.f};

  const unsigned short* kbase = kb + (int64_t)b * TKV * 1024 + h * DH;
  const unsigned short* vbase = vbt + (int64_t)bh * DH * TKV;
  const float* mbase = mask + (int64_t)(q0 + hi * 4) * TKV;

  for (int c = 0; c < 16; c++) {
    int kv0 = c * 64;
#pragma unroll
    for (int e = tid; e < 512; e += 256) {
      int r = e >> 3, kc = (e & 7) * 8;
      *(bf16x8*)&Ks[r * 72 + kc] = *(const bf16x8*)&kbase[(int64_t)(kv0 + r) * 1024 + kc];
      *(bf16x8*)&Vs[r * 72 + kc] = *(const bf16x8*)&vbase[(int64_t)r * TKV + kv0 + kc];
    }
    __syncthreads();

    f32x4 s[4];
#pragma unroll
    for (int nt = 0; nt < 4; nt++) {
      bf16x8 bk0 = *(const bf16x8*)&Ks[(nt * 16 + lr) * 72 + hi * 8];
      bf16x8 bk1 = *(const bf16x8*)&Ks[(nt * 16 + lr) * 72 + 32 + hi * 8];
      f32x4 z = (f32x4){0.f, 0.f, 0.f, 0.f};
      z = __builtin_amdgcn_mfma_f32_16x16x32_bf16(aq0, bk0, z, 0, 0, 0);
      z = __builtin_amdgcn_mfma_f32_16x16x32_bf16(aq1, bk1, z, 0, 0, 0);
      s[nt] = z;
    }
    // + mask
#pragma unroll
    for (int nt = 0; nt < 4; nt++)
#pragma unroll
      for (int r = 0; r < 4; r++)
        s[nt][r] += mbase[(int64_t)r * TKV + kv0 + nt * 16 + lr];

    // online softmax (rows hi*4+r live in 16-lane groups)
    float cm[4];
#pragma unroll
    for (int r = 0; r < 4; r++) {
      cm[r] = fmaxf(fmaxf(s[0][r], s[1][r]), fmaxf(s[2][r], s[3][r]));
#pragma unroll
      for (int d = 1; d < 16; d <<= 1) cm[r] = fmaxf(cm[r], __shfl_xor(cm[r], d));
    }
    float al[4], rs[4];
#pragma unroll
    for (int r = 0; r < 4; r++) {
      float nm = fmaxf(m[r], cm[r]);
      al[r] = __expf(m[r] - nm);
      m[r] = nm;
      rs[r] = 0.f;
    }
#pragma unroll
    for (int nt = 0; nt < 4; nt++)
#pragma unroll
      for (int r = 0; r < 4; r++) {
        s[nt][r] = __expf(s[nt][r] - m[r]);
        rs[r] += s[nt][r];
      }
#pragma unroll
    for (int r = 0; r < 4; r++) {
#pragma unroll
      for (int d = 1; d < 16; d <<= 1) rs[r] += __shfl_xor(rs[r], d);
      l[r] = l[r] * al[r] + rs[r];
    }
#pragma unroll
    for (int nt = 0; nt < 4; nt++)
#pragma unroll
      for (int r = 0; r < 4; r++) o[nt][r] *= al[r];

    // P -> bf16 -> LDS (re-layout for A-operand)
#pragma unroll
    for (int nt = 0; nt < 4; nt++)
#pragma unroll
      for (int r = 0; r < 4; r++)
        Ps[w][(hi * 4 + r) * 72 + nt * 16 + lr] = f2bf(s[nt][r]);
    __syncthreads();

    bf16x8 pa0 = *(const bf16x8*)&Ps[w][lr * 72 + hi * 8];
    bf16x8 pa1 = *(const bf16x8*)&Ps[w][lr * 72 + 32 + hi * 8];
#pragma unroll
    for (int nt = 0; nt < 4; nt++) {
      bf16x8 bv0 = *(const bf16x8*)&Vs[(nt * 16 + lr) * 72 + hi * 8];
      bf16x8 bv1 = *(const bf16x8*)&Vs[(nt * 16 + lr) * 72 + 32 + hi * 8];
      o[nt] = __builtin_amdgcn_mfma_f32_16x16x32_bf16(pa0, bv0, o[nt], 0, 0, 0);
      o[nt] = __builtin_amdgcn_mfma_f32_16x16x32_bf16(pa1, bv1, o[nt], 0, 0, 0);
    }
    __syncthreads();
  }

  float inv[4];
#pragma unroll
  for (int r = 0; r < 4; r++) inv[r] = 1.f / l[r];
#pragma unroll
  for (int nt = 0; nt < 4; nt++)
#pragma unroll
    for (int r = 0; r < 4; r++)
      wvb[(int64_t)(b * Tt + q0 + hi * 4 + r) * 1024 + h * DH + nt * 16 + lr] =
          f2bf(o[nt][r] * inv[r]);
}

// ---------------------------------------------------------------------------
extern "C" void kernel_launch(void* const* d_in, const int* in_sizes, int n_in,
                              void* d_out, int out_size, void* d_ws, size_t ws_size,
                              hipStream_t stream) {
  const float* x    = (const float*)d_in[0];
  const float* mask = (const float*)d_in[1];
  const float* ck   = (const float*)d_in[2];
  const float* cv   = (const float*)d_in[3];
  const float* Wq   = (const float*)d_in[4];
  const float* bq   = (const float*)d_in[5];
  const float* Wk   = (const float*)d_in[6];
  const float* Wv   = (const float*)d_in[7];
  const float* bv   = (const float*)d_in[8];
  const float* Wo   = (const float*)d_in[9];
  const float* bo   = (const float*)d_in[10];

  const int64_t NT = (int64_t)Bb * Tt * NS;   // 2097152
  float* outp = (float*)d_out;
  float* okf  = outp + NT;
  float* ovf  = outp + 2 * NT;

  char* ws = (char*)d_ws;
  unsigned short* xb  = (unsigned short*)(ws);                       // 4 MB
  unsigned short* wqt = (unsigned short*)(ws + (4LL << 20));         // 2 MB each
  unsigned short* wkt = (unsigned short*)(ws + (6LL << 20));
  unsigned short* wvt = (unsigned short*)(ws + (8LL << 20));
  unsigned short* wot = (unsigned short*)(ws + (10LL << 20));
  unsigned short* qbw = (unsigned short*)(ws + (12LL << 20));        // 4 MB
  unsigned short* kbw = (unsigned short*)(ws + (16LL << 20));        // 16 MB
  unsigned short* vbt = (unsigned short*)(ws + (32LL << 20));        // 16 MB
  unsigned short* wvb = (unsigned short*)(ws + (48LL << 20));        // 4 MB

  convert_flat<<<2048, 256, 0, stream>>>(x, ck, xb, kbw);
  transpose_convert<<<2560, 256, 0, stream>>>(Wq, Wk, Wv, Wo, cv, wqt, wkt, wvt, wot, vbt);
  gemm128<0><<<384, 256, 0, stream>>>(xb, wqt, wkt, wvt, bq, bv, bo,
                                      qbw, okf, ovf, kbw, vbt, outp);
  attn<<<512, 256, 0, stream>>>(qbw, kbw, vbt, mask, wvb);
  gemm128<1><<<128, 256, 0, stream>>>(wvb, wot, wot, wot, bq, bv, bo,
                                      qbw, okf, ovf, kbw, vbt, outp);
}